// Round 1
// baseline (113.720 us; speedup 1.0000x reference)
//
#include <hip/hip_runtime.h>
#include <math.h>

// Depthwise 5x5 Gaussian blur, sigma from device scalar.
// x: (16, 256, 64, 64) fp32, out same. Zero padding 2.
// One block per (n,c) plane; separable conv via two LDS passes.

constexpr int Hh   = 64;
constexpr int Ww   = 64;
constexpr int KS   = 5;
constexpr int PADc = 2;
constexpr int TH   = Hh + 2 * PADc;  // 68 padded rows
constexpr int IN_STR  = 72;          // 72*4B = 288B row stride -> 16B aligned rows
constexpr int TMP_STR = 64;

__global__ __launch_bounds__(256, 4) void gauss5(const float* __restrict__ x,
                                                 const float* __restrict__ sigma,
                                                 float* __restrict__ out) {
    __shared__ float sIn[TH * IN_STR];    // 68x72 padded input plane (19.1 KB)
    __shared__ float sTmp[TH * TMP_STR];  // 68x64 horizontal-pass result (17.4 KB)

    const int t = threadIdx.x;
    const size_t plane = blockIdx.x;  // n*C + c
    const float* __restrict__ xp = x + plane * (size_t)(Hh * Ww);
    float* __restrict__ op = out + plane * (size_t)(Hh * Ww);

    // --- normalized 1-D Gaussian taps (outer product of these sums to 1,
    //     matching the reference's k2d / k2d.sum()) ---
    const float sg = sigma[0];
    const float c2 = -1.0f / (2.0f * sg * sg);
    float g[KS];
    float gsum = 0.0f;
#pragma unroll
    for (int i = 0; i < KS; ++i) {
        float d = (float)(i - PADc);
        g[i] = expf(d * d * c2);
        gsum += g[i];
    }
    const float ginv = 1.0f / gsum;
#pragma unroll
    for (int i = 0; i < KS; ++i) g[i] *= ginv;

    // --- zero the padded input tile (halo must be 0) ---
    for (int i = t; i < TH * IN_STR; i += 256) sIn[i] = 0.0f;
    __syncthreads();

    // --- load 64x64 plane into interior (float4 coalesced global reads) ---
    const float4* __restrict__ x4 = (const float4*)xp;
#pragma unroll
    for (int k = 0; k < 4; ++k) {
        int idx = t + k * 256;        // float4 index 0..1023
        int r   = idx >> 4;           // 16 float4 per row
        int c   = (idx & 15) << 2;
        float4 v = x4[idx];
        float* dst = &sIn[(r + PADc) * IN_STR + c + PADc];
        dst[0] = v.x; dst[1] = v.y; dst[2] = v.z; dst[3] = v.w;
    }
    __syncthreads();

    // --- horizontal pass: all 68 padded rows, 64 output cols, 4 per thread ---
    // output col c needs padded cols c..c+4; window [c4*4, c4*4+8) is two
    // aligned float4 LDS reads.
    for (int idx = t; idx < TH * (Ww / 4); idx += 256) {  // 1088 quads
        int r  = idx >> 4;
        int c4 = idx & 15;
        const float* src = &sIn[r * IN_STR + (c4 << 2)];
        float4 a = *(const float4*)(src);
        float4 b = *(const float4*)(src + 4);
        float f0 = a.x, f1 = a.y, f2 = a.z, f3 = a.w;
        float f4 = b.x, f5 = b.y, f6 = b.z, f7 = b.w;
        float4 o;
        o.x = g[0]*f0 + g[1]*f1 + g[2]*f2 + g[3]*f3 + g[4]*f4;
        o.y = g[0]*f1 + g[1]*f2 + g[2]*f3 + g[3]*f4 + g[4]*f5;
        o.z = g[0]*f2 + g[1]*f3 + g[2]*f4 + g[3]*f5 + g[4]*f6;
        o.w = g[0]*f3 + g[1]*f4 + g[2]*f5 + g[3]*f6 + g[4]*f7;
        *(float4*)&sTmp[r * TMP_STR + (c4 << 2)] = o;
    }
    __syncthreads();

    // --- vertical pass + coalesced float4 store ---
    // output row r needs tmp rows r..r+4 (tmp row tr = image row tr-2).
    float4* __restrict__ o4 = (float4*)op;
#pragma unroll
    for (int k = 0; k < 4; ++k) {
        int idx = t + k * 256;        // 0..1023
        int r   = idx >> 4;
        int c4  = idx & 15;
        const float* base = &sTmp[r * TMP_STR + (c4 << 2)];
        float4 acc = make_float4(0.f, 0.f, 0.f, 0.f);
#pragma unroll
        for (int j = 0; j < KS; ++j) {
            float4 v = *(const float4*)(base + j * TMP_STR);
            acc.x += g[j] * v.x;
            acc.y += g[j] * v.y;
            acc.z += g[j] * v.z;
            acc.w += g[j] * v.w;
        }
        o4[idx] = acc;
    }
}

extern "C" void kernel_launch(void* const* d_in, const int* in_sizes, int n_in,
                              void* d_out, int out_size, void* d_ws, size_t ws_size,
                              hipStream_t stream) {
    const float* x     = (const float*)d_in[0];
    const float* sigma = (const float*)d_in[1];
    float* out         = (float*)d_out;
    const int planes = in_sizes[0] / (Hh * Ww);  // 16*256 = 4096
    gauss5<<<planes, 256, 0, stream>>>(x, sigma, out);
}